// Round 5
// baseline (58.118 us; speedup 1.0000x reference)
//
#include <hip/hip_runtime.h>
#include <climits>

// Problem constants (fixed by the reference): B=32, T=8192, M=128.
#define TT 8192
#define MM 128
#define NTHREADS 256
#define CH 32                   // labels per thread (TT / NTHREADS)
#define SLICES 64
#define SLICE (TT / SLICES)     // 128 frames applied per block

typedef float f32x4 __attribute__((ext_vector_type(4)));

// ---------------------------------------------------------------------------
// Fused kernel, one 256-thread block per (row, 128-frame slice).
// Labels live in REGISTERS (8 packed words of 4 byte-labels each) — no LDS
// label tile, so LDS is ~1.7 KB and 8 blocks/CU co-reside; scan/walk phases
// of some blocks hide under the streaming phase of others.
// ---------------------------------------------------------------------------
__global__ __launch_bounds__(NTHREADS, 8)
void fused_kernel(const int* __restrict__ labels,
                  const f32x4* __restrict__ mel,
                  f32x4* __restrict__ out)
{
    __shared__ int2 pls[SLICE];        // 1 KiB slice params
    __shared__ int  stbuf[4][CH];      // 512 B walk scratch (4 walk threads)
    __shared__ int  wS[4], wE[4];      // wave totals

    const int tid   = threadIdx.x;
    const int lane  = tid & 63;
    const int wid   = tid >> 6;
    const int b     = blockIdx.x >> 6;       // SLICES = 64
    const int slice = blockIdx.x & 63;
    const int sbase = slice * SLICE;
    const int* lrow = labels + (size_t)b * TT;
    const int4* lrow4 = (const int4*)lrow;

    const int base = tid * CH;

    // Load own 32-label chunk, pack 4 byte-labels per word (labels are 0..7).
    int packed[8];
#pragma unroll
    for (int w = 0; w < 8; ++w) {
        int4 q = lrow4[tid * 8 + w];
        packed[w] = q.x | (q.y << 8) | (q.z << 16) | (q.w << 24);
    }
    const int prevLab = (tid == 0)            ? -1 : lrow[base - 1];
    const int nextLab = (tid == NTHREADS - 1) ? -1 : lrow[base + CH];

    // Per-chunk summaries from registers. Ascending keeps the LAST change;
    // descending keeps overwriting so the FINAL value is the SMALLEST end
    // boundary (latch-on-first-hit grabs the largest — R2's bug).
    int lastChange = -1, firstEnd = INT_MAX;
    {
        int prev = prevLab;
#pragma unroll
        for (int w = 0; w < 8; ++w) {
            int pw = packed[w];
#pragma unroll
            for (int k = 0; k < 4; ++k) {
                int cur = (pw >> (8 * k)) & 255;
                if (cur != prev) lastChange = base + w * 4 + k;
                prev = cur;
            }
        }
        int nxt = nextLab;
#pragma unroll
        for (int w = 7; w >= 0; --w) {
            int pw = packed[w];
#pragma unroll
            for (int k = 3; k >= 0; --k) {
                int cur = (pw >> (8 * k)) & 255;
                if (cur != nxt) firstEnd = base + w * 4 + k + 1;
                nxt = cur;
            }
        }
    }

    // Wave-level inclusive scans: max from the left, min from the right.
    int inclS = lastChange;
#pragma unroll
    for (int off = 1; off < 64; off <<= 1) {
        int u = __shfl_up(inclS, off);
        if (lane >= off) inclS = max(inclS, u);
    }
    int inclE = firstEnd;
#pragma unroll
    for (int off = 1; off < 64; off <<= 1) {
        int u = __shfl_down(inclE, off);
        if (lane + off < 64) inclE = min(inclE, u);
    }

    if (lane == 63) wS[wid] = inclS;
    if (lane == 0)  wE[wid] = inclE;
    __syncthreads();

    int waveCarryS = -1, waveCarryE = TT;
#pragma unroll
    for (int j = 0; j < 4; ++j) {
        if (j < wid) waveCarryS = max(waveCarryS, wS[j]);
        if (j > wid) waveCarryE = min(waveCarryE, wE[j]);
    }

    int prevIncl   = __shfl_up(inclS, 1);
    int carryStart = (lane == 0)  ? waveCarryS : max(prevIncl, waveCarryS);
    int nextIncl   = __shfl_down(inclE, 1);
    int carryEnd   = (lane == 63) ? waveCarryE : min(nextIncl, waveCarryE);

    // Walk + param emit: only the 4 threads whose chunks form our slice.
    if ((tid >> 2) == slice) {
        const int widx = tid & 3;

        // Ascending: per-frame segment start into LDS scratch.
        int curst = carryStart;
        int prev  = prevLab;
#pragma unroll
        for (int w = 0; w < 8; ++w) {
            int pw = packed[w];
#pragma unroll
            for (int k = 0; k < 4; ++k) {
                int cur = (pw >> (8 * k)) & 255;
                if (cur != prev) curst = base + w * 4 + k;
                prev = cur;
                stbuf[widx][w * 4 + k] = curst;
            }
        }

        // Descending: per-frame segment end + emit params.
        int curEnd = carryEnd;
        int nxt    = nextLab;
#pragma unroll
        for (int w = 7; w >= 0; --w) {
            int pw = packed[w];
#pragma unroll
            for (int k = 3; k >= 0; --k) {
                int t   = base + w * 4 + k;
                int cur = (pw >> (8 * k)) & 255;
                if (cur != nxt) curEnd = t + 1;
                nxt = cur;

                int start   = stbuf[widx][w * 4 + k];
                int seg_len = curEnd - start;
                int pos     = t - start;
                float frac  = (float)pos / (float)max(seg_len - 1, 1);

                int  s   = t;                 // row-local source frame
                bool eff = false;
                float g  = (cur == 0 || cur == 7) ? 0.0f : 1.0f;

                if (cur == 2) {                       // LOOP
                    int Lp = min(seg_len, start);
                    if (Lp > 0) {
                        s = start - Lp + (pos % Lp);  // in [0, start)
                        int Ls = lrow[s];
                        g = (Ls == 0 || Ls == 7) ? 0.0f : 1.0f;
                    }
                } else if (cur == 3) {                // FADE_IN
                    g = frac;
                } else if (cur == 4) {                // FADE_OUT
                    g = 1.0f - frac;
                } else if (cur == 6) {                // TRANSITION
                    g = 1.0f - 0.5f * __sinf(3.14159265358979323846f * frac);
                } else if (cur == 5) {                // EFFECT (low-pass)
                    eff = true;
                }

                pls[t - sbase] = make_int2(s | (eff ? (1 << 30) : 0),
                                           __float_as_int(g));
            }
        }
    }
    __syncthreads();

    // Streaming apply: 32 lanes per frame, float4 per lane; 8 frames/iter.
    const int    alane  = tid & 31;                    // m = alane*4..+3
    const float  lpmul  = (alane >= 16) ? 0.3f : 1.0f; // m >= 64 -> 0.3
    const size_t rowb   = (size_t)b * TT * 32;         // float4 units

#pragma unroll
    for (int i = 0; i < SLICE / 8; ++i) {
        int  fidx = i * 8 + (tid >> 5);                // 0..127 within slice
        int2 p    = pls[fidx];                         // broadcast, no conflict
        float g   = __int_as_float(p.y);
        f32x4 r = {0.0f, 0.0f, 0.0f, 0.0f};
        if (g != 0.0f) {
            int   src = p.x & 0x3FFFFFFF;
            float gm  = (p.x >> 30) ? g * lpmul : g;
            f32x4 v = mel[rowb + (size_t)src * 32 + alane];
            r.x = fminf(fmaxf(v.x * gm, 0.0f), 1.0f);
            r.y = fminf(fmaxf(v.y * gm, 0.0f), 1.0f);
            r.z = fminf(fmaxf(v.z * gm, 0.0f), 1.0f);
            r.w = fminf(fmaxf(v.w * gm, 0.0f), 1.0f);
        }
        __builtin_nontemporal_store(
            r, &out[rowb + (size_t)(sbase + fidx) * 32 + alane]);
    }
}

extern "C" void kernel_launch(void* const* d_in, const int* in_sizes, int n_in,
                              void* d_out, int out_size, void* d_ws, size_t ws_size,
                              hipStream_t stream)
{
    const float* mel    = (const float*)d_in[0];
    const int*   labels = (const int*)d_in[1];
    float*       out    = (float*)d_out;

    const int nframes = out_size / MM;        // B*T = 262144
    const int B       = nframes / TT;         // 32

    fused_kernel<<<B * SLICES, NTHREADS, 0, stream>>>(
        labels, (const f32x4*)mel, (f32x4*)out);
}

// Round 6
// 53.782 us; speedup vs baseline: 1.0806x; 1.0806x over previous
//
#include <hip/hip_runtime.h>
#include <climits>

// Problem constants (fixed by the reference): B=32, T=8192, M=128.
#define TT 8192
#define MM 128
#define SEG_THREADS 1024
#define CH (TT / SEG_THREADS)   // 8 frames per thread

typedef float f32x4 __attribute__((ext_vector_type(4)));

// ---------------------------------------------------------------------------
// Kernel 1: per-row segment analysis (R3-verified structure). One block
// (16 waves) per batch row. Emits per frame an int2:
// {abs source frame | effect bit<<30, gain bits}.
// ---------------------------------------------------------------------------
__global__ __launch_bounds__(SEG_THREADS)
void seg_kernel(const int* __restrict__ labels, int2* __restrict__ params)
{
    __shared__ int lab[TT];        // 32 KiB
    __shared__ int wtotS[16], wtotE[16], wscanS[16], wscanE[16];

    const int tid  = threadIdx.x;
    const int lane = tid & 63;
    const int wid  = tid >> 6;
    const int b    = blockIdx.x;
    const int* lrow = labels + (size_t)b * TT;

    // Coalesced int4 label staging (2 iters).
    {
        const int4* lrow4 = (const int4*)lrow;
        int4* lab4 = (int4*)lab;
        for (int i = tid; i < TT / 4; i += SEG_THREADS) lab4[i] = lrow4[i];
    }
    __syncthreads();

    const int base = tid * CH;

    // Per-chunk summaries: last segment-start (max), first segment-end (min).
    // Descending loop keeps overwriting so the FINAL value is the smallest
    // t+1 (latch-on-first-hit grabs the largest — R2's bug).
    int lastChange = -1;
    int firstEnd   = INT_MAX;
#pragma unroll
    for (int k = 0; k < CH; ++k) {
        int t = base + k;
        if ((t == 0) || (lab[t] != lab[t - 1])) lastChange = t;
    }
#pragma unroll
    for (int k = CH - 1; k >= 0; --k) {
        int t = base + k;
        if ((t == TT - 1) || (lab[t] != lab[t + 1])) firstEnd = t + 1;
    }

    // Wave-level inclusive scans: max from the left, min from the right.
    int inclS = lastChange;
#pragma unroll
    for (int off = 1; off < 64; off <<= 1) {
        int u = __shfl_up(inclS, off);
        if (lane >= off) inclS = max(inclS, u);
    }
    int inclE = firstEnd;
#pragma unroll
    for (int off = 1; off < 64; off <<= 1) {
        int u = __shfl_down(inclE, off);
        if (lane + off < 64) inclE = min(inclE, u);
    }

    if (lane == 63) wtotS[wid] = inclS;
    if (lane == 0)  wtotE[wid] = inclE;
    __syncthreads();

    // Cross-wave carries: wave 0 scans the 16 start-totals, wave 1 the ends.
    if (tid < 16) {
        int v = wtotS[tid];
#pragma unroll
        for (int off = 1; off < 16; off <<= 1) {
            int u = __shfl_up(v, off);
            if (tid >= off) v = max(v, u);
        }
        wscanS[tid] = v;
    } else if (tid >= 64 && tid < 80) {
        int l = tid - 64;
        int v = wtotE[l];
#pragma unroll
        for (int off = 1; off < 16; off <<= 1) {
            int u = __shfl_down(v, off);
            if (l + off < 16) v = min(v, u);
        }
        wscanE[l] = v;
    }
    __syncthreads();

    int waveCarryS = (wid > 0)  ? wscanS[wid - 1] : -1;
    int waveCarryE = (wid < 15) ? wscanE[wid + 1] : TT;

    int prevIncl   = __shfl_up(inclS, 1);
    int carryStart = (lane == 0)  ? waveCarryS : max(prevIncl, waveCarryS);
    int nextIncl   = __shfl_down(inclE, 1);
    int carryEnd   = (lane == 63) ? waveCarryE : min(nextIncl, waveCarryE);

    // Forward walk: per-frame segment start.
    int st[CH];
    int cur = carryStart;
#pragma unroll
    for (int k = 0; k < CH; ++k) {
        int t = base + k;
        if ((t == 0) || (lab[t] != lab[t - 1])) cur = t;
        st[k] = cur;
    }

    // Backward walk: per-frame segment end + emit params.
    int curEnd = carryEnd;
#pragma unroll
    for (int k = CH - 1; k >= 0; --k) {
        int t = base + k;
        if ((t == TT - 1) || (lab[t] != lab[t + 1])) curEnd = t + 1;

        int L       = lab[t];
        int start   = st[k];
        int seg_len = curEnd - start;
        int pos     = t - start;
        float frac  = (float)pos / (float)max(seg_len - 1, 1);

        int  s    = t;
        bool eff  = false;
        float g   = (L == 0 || L == 7) ? 0.0f : 1.0f;

        if (L == 2) {                         // LOOP: tile preceding frames
            int Lp = min(seg_len, start);
            if (Lp > 0) {
                s = start - Lp + (pos % Lp);  // in [0, start)
                int Ls = lab[s];
                g = (Ls == 0 || Ls == 7) ? 0.0f : 1.0f;  // keep-mask of source
            }
        } else if (L == 3) {                  // FADE_IN
            g = frac;
        } else if (L == 4) {                  // FADE_OUT
            g = 1.0f - frac;
        } else if (L == 6) {                  // TRANSITION
            g = 1.0f - 0.5f * sinf(3.14159265358979323846f * frac);
        } else if (L == 5) {                  // EFFECT (low-pass)
            eff = true;
        }

        params[b * TT + t] = make_int2((b * TT + s) | (eff ? (1 << 30) : 0),
                                       __float_as_int(g));
    }
}

// ---------------------------------------------------------------------------
// Kernel 2: streaming apply, branch-free, 2 frames per thread per iteration
// for memory ILP. 32 lanes per frame, float4 per lane. nt-stores keep `out`
// from evicting the L3-resident mel (R5 counters: FETCH ~45 MB).
// ---------------------------------------------------------------------------
__global__ __launch_bounds__(256)
void apply_kernel(const f32x4* __restrict__ mel,
                  const int2* __restrict__ params,
                  f32x4* __restrict__ out, int nframes)
{
    const int tid   = threadIdx.x;
    const int lane  = tid & 31;         // m-chunk: m = lane*4 .. lane*4+3
    const int fin   = tid >> 5;         // 0..7
    const int fstep = gridDim.x * 16;   // 16 frames per block per iteration
    const float lpmul = (lane >= 16) ? 0.3f : 1.0f;  // m >= 64 -> 0.3

    for (int base = blockIdx.x * 16; base < nframes; base += fstep) {
        int f0 = base + fin;
        int f1 = base + 8 + fin;

        int2 p0 = params[f0];
        int2 p1 = params[f1];

        int   src0 = p0.x & 0x3FFFFFFF;
        int   src1 = p1.x & 0x3FFFFFFF;
        float g0   = __int_as_float(p0.y);
        float g1   = __int_as_float(p1.y);
        float gm0  = (p0.x >> 30) ? g0 * lpmul : g0;
        float gm1  = (p1.x >> 30) ? g1 * lpmul : g1;

        // Both loads issued back-to-back (independent) before either use.
        f32x4 v0 = mel[(size_t)src0 * 32 + lane];
        f32x4 v1 = mel[(size_t)src1 * 32 + lane];

        f32x4 r0, r1;
        r0.x = fminf(fmaxf(v0.x * gm0, 0.0f), 1.0f);
        r0.y = fminf(fmaxf(v0.y * gm0, 0.0f), 1.0f);
        r0.z = fminf(fmaxf(v0.z * gm0, 0.0f), 1.0f);
        r0.w = fminf(fmaxf(v0.w * gm0, 0.0f), 1.0f);
        r1.x = fminf(fmaxf(v1.x * gm1, 0.0f), 1.0f);
        r1.y = fminf(fmaxf(v1.y * gm1, 0.0f), 1.0f);
        r1.z = fminf(fmaxf(v1.z * gm1, 0.0f), 1.0f);
        r1.w = fminf(fmaxf(v1.w * gm1, 0.0f), 1.0f);

        __builtin_nontemporal_store(r0, &out[(size_t)f0 * 32 + lane]);
        __builtin_nontemporal_store(r1, &out[(size_t)f1 * 32 + lane]);
    }
}

extern "C" void kernel_launch(void* const* d_in, const int* in_sizes, int n_in,
                              void* d_out, int out_size, void* d_ws, size_t ws_size,
                              hipStream_t stream)
{
    const float* mel    = (const float*)d_in[0];
    const int*   labels = (const int*)d_in[1];
    float*       out    = (float*)d_out;

    const int nframes = out_size / MM;       // B*T = 262144
    const int B       = nframes / TT;        // 32

    int2* params = (int2*)d_ws;              // 2 MiB

    seg_kernel<<<B, SEG_THREADS, 0, stream>>>(labels, params);

    const int blocks = 2048;                 // 8 blocks/CU, 8 iterations each
    apply_kernel<<<blocks, 256, 0, stream>>>((const f32x4*)mel, params,
                                             (f32x4*)out, nframes);
}

// Round 7
// 46.732 us; speedup vs baseline: 1.2436x; 1.1509x over previous
//
#include <hip/hip_runtime.h>
#include <climits>

// Problem constants (fixed by the reference): B=32, T=8192, M=128.
#define TT 8192
#define MM 128
#define SEG_THREADS 1024
#define CH (TT / SEG_THREADS)   // 8 frames per thread

typedef float f32x4 __attribute__((ext_vector_type(4)));

// ---------------------------------------------------------------------------
// Kernel 1: per-row segment analysis (R3-verified structure). One block
// (16 waves) per batch row. Emits per frame an int2:
// {abs source frame | effect bit<<30, gain bits}.
// ---------------------------------------------------------------------------
__global__ __launch_bounds__(SEG_THREADS)
void seg_kernel(const int* __restrict__ labels, int2* __restrict__ params)
{
    __shared__ int lab[TT];        // 32 KiB
    __shared__ int wtotS[16], wtotE[16], wscanS[16], wscanE[16];

    const int tid  = threadIdx.x;
    const int lane = tid & 63;
    const int wid  = tid >> 6;
    const int b    = blockIdx.x;
    const int* lrow = labels + (size_t)b * TT;

    // Coalesced int4 label staging (2 iters).
    {
        const int4* lrow4 = (const int4*)lrow;
        int4* lab4 = (int4*)lab;
        for (int i = tid; i < TT / 4; i += SEG_THREADS) lab4[i] = lrow4[i];
    }
    __syncthreads();

    const int base = tid * CH;

    // Per-chunk summaries: last segment-start (max), first segment-end (min).
    // Descending loop keeps overwriting so the FINAL value is the smallest
    // t+1 (latch-on-first-hit grabs the largest — R2's bug).
    int lastChange = -1;
    int firstEnd   = INT_MAX;
#pragma unroll
    for (int k = 0; k < CH; ++k) {
        int t = base + k;
        if ((t == 0) || (lab[t] != lab[t - 1])) lastChange = t;
    }
#pragma unroll
    for (int k = CH - 1; k >= 0; --k) {
        int t = base + k;
        if ((t == TT - 1) || (lab[t] != lab[t + 1])) firstEnd = t + 1;
    }

    // Wave-level inclusive scans: max from the left, min from the right.
    int inclS = lastChange;
#pragma unroll
    for (int off = 1; off < 64; off <<= 1) {
        int u = __shfl_up(inclS, off);
        if (lane >= off) inclS = max(inclS, u);
    }
    int inclE = firstEnd;
#pragma unroll
    for (int off = 1; off < 64; off <<= 1) {
        int u = __shfl_down(inclE, off);
        if (lane + off < 64) inclE = min(inclE, u);
    }

    if (lane == 63) wtotS[wid] = inclS;
    if (lane == 0)  wtotE[wid] = inclE;
    __syncthreads();

    // Cross-wave carries: wave 0 scans the 16 start-totals, wave 1 the ends.
    if (tid < 16) {
        int v = wtotS[tid];
#pragma unroll
        for (int off = 1; off < 16; off <<= 1) {
            int u = __shfl_up(v, off);
            if (tid >= off) v = max(v, u);
        }
        wscanS[tid] = v;
    } else if (tid >= 64 && tid < 80) {
        int l = tid - 64;
        int v = wtotE[l];
#pragma unroll
        for (int off = 1; off < 16; off <<= 1) {
            int u = __shfl_down(v, off);
            if (l + off < 16) v = min(v, u);
        }
        wscanE[l] = v;
    }
    __syncthreads();

    int waveCarryS = (wid > 0)  ? wscanS[wid - 1] : -1;
    int waveCarryE = (wid < 15) ? wscanE[wid + 1] : TT;

    int prevIncl   = __shfl_up(inclS, 1);
    int carryStart = (lane == 0)  ? waveCarryS : max(prevIncl, waveCarryS);
    int nextIncl   = __shfl_down(inclE, 1);
    int carryEnd   = (lane == 63) ? waveCarryE : min(nextIncl, waveCarryE);

    // Forward walk: per-frame segment start.
    int st[CH];
    int cur = carryStart;
#pragma unroll
    for (int k = 0; k < CH; ++k) {
        int t = base + k;
        if ((t == 0) || (lab[t] != lab[t - 1])) cur = t;
        st[k] = cur;
    }

    // Backward walk: per-frame segment end + emit params.
    int curEnd = carryEnd;
#pragma unroll
    for (int k = CH - 1; k >= 0; --k) {
        int t = base + k;
        if ((t == TT - 1) || (lab[t] != lab[t + 1])) curEnd = t + 1;

        int L       = lab[t];
        int start   = st[k];
        int seg_len = curEnd - start;
        int pos     = t - start;
        float frac  = (float)pos / (float)max(seg_len - 1, 1);

        int  s    = t;
        bool eff  = false;
        float g   = (L == 0 || L == 7) ? 0.0f : 1.0f;

        if (L == 2) {                         // LOOP: tile preceding frames
            int Lp = min(seg_len, start);
            if (Lp > 0) {
                s = start - Lp + (pos % Lp);  // in [0, start)
                int Ls = lab[s];
                g = (Ls == 0 || Ls == 7) ? 0.0f : 1.0f;  // keep-mask of source
            }
        } else if (L == 3) {                  // FADE_IN
            g = frac;
        } else if (L == 4) {                  // FADE_OUT
            g = 1.0f - frac;
        } else if (L == 6) {                  // TRANSITION
            g = 1.0f - 0.5f * sinf(3.14159265358979323846f * frac);
        } else if (L == 5) {                  // EFFECT (low-pass)
            eff = true;
        }

        params[b * TT + t] = make_int2((b * TT + s) | (eff ? (1 << 30) : 0),
                                       __float_as_int(g));
    }
}

// ---------------------------------------------------------------------------
// Kernel 2: streaming apply. 4 frames per thread per iteration with distinct
// registers per frame (launch_bounds(256,4) -> ~128 VGPR budget) so nt-store
// data registers aren't reused until vmcnt distance >= 4 — R6's VGPR=16
// build serialized on store completion (1.76 TB/s write). g==0 frames skip
// the mel fetch; nt-stores keep `out` from evicting L3-resident mel.
// ---------------------------------------------------------------------------
__global__ __launch_bounds__(256, 4)
void apply_kernel(const f32x4* __restrict__ mel,
                  const int2* __restrict__ params,
                  f32x4* __restrict__ out, int nframes)
{
    const int tid   = threadIdx.x;
    const int lane  = tid & 31;         // m-chunk: m = lane*4 .. lane*4+3
    const int fin   = tid >> 5;         // 0..7
    const int fstep = gridDim.x * 32;   // 32 frames per block per iteration
    const float lpmul = (lane >= 16) ? 0.3f : 1.0f;  // m >= 64 -> 0.3

    for (int base = blockIdx.x * 32; base < nframes; base += fstep) {
        int f[4];
        int2 p[4];
#pragma unroll
        for (int u = 0; u < 4; ++u) {
            f[u] = base + u * 8 + fin;
            p[u] = params[f[u]];
        }

        f32x4 v[4];
#pragma unroll
        for (int u = 0; u < 4; ++u) {
            float g = __int_as_float(p[u].y);
            v[u] = (f32x4){0.0f, 0.0f, 0.0f, 0.0f};
            if (g != 0.0f) {
                int src = p[u].x & 0x3FFFFFFF;
                v[u] = mel[(size_t)src * 32 + lane];
            }
        }

        f32x4 r[4];
#pragma unroll
        for (int u = 0; u < 4; ++u) {
            float g  = __int_as_float(p[u].y);
            float gm = (p[u].x >> 30) ? g * lpmul : g;
            r[u].x = fminf(fmaxf(v[u].x * gm, 0.0f), 1.0f);
            r[u].y = fminf(fmaxf(v[u].y * gm, 0.0f), 1.0f);
            r[u].z = fminf(fmaxf(v[u].z * gm, 0.0f), 1.0f);
            r[u].w = fminf(fmaxf(v[u].w * gm, 0.0f), 1.0f);
        }

#pragma unroll
        for (int u = 0; u < 4; ++u)
            __builtin_nontemporal_store(r[u], &out[(size_t)f[u] * 32 + lane]);
    }
}

extern "C" void kernel_launch(void* const* d_in, const int* in_sizes, int n_in,
                              void* d_out, int out_size, void* d_ws, size_t ws_size,
                              hipStream_t stream)
{
    const float* mel    = (const float*)d_in[0];
    const int*   labels = (const int*)d_in[1];
    float*       out    = (float*)d_out;

    const int nframes = out_size / MM;       // B*T = 262144
    const int B       = nframes / TT;        // 32

    int2* params = (int2*)d_ws;              // 2 MiB

    seg_kernel<<<B, SEG_THREADS, 0, stream>>>(labels, params);

    const int blocks = 2048;                 // 4 iterations of 32 frames each
    apply_kernel<<<blocks, 256, 0, stream>>>((const f32x4*)mel, params,
                                             (f32x4*)out, nframes);
}